// Round 2
// baseline (367.349 us; speedup 1.0000x reference)
//
#include <hip/hip_runtime.h>
#include <math.h>

#define TOKS 16384
#define CDIM 128
#define NH 4
#define HD 32
#define HID 512
#define QSCALE 0.17677669529663687f
#define LEPS 1e-5f

typedef const float* fp;

// ---------------- k1: LN1 + QKV GEMM (16 tokens per block, 384 threads) ----------------
__global__ __launch_bounds__(384) void k1_ln_qkv(fp x, fp g, fp b, fp w, fp wb,
                                                 float* __restrict__ qkv) {
    __shared__ float xn[16 * 132];
    __shared__ float mu[16], rs[16];
    const int base = blockIdx.x * 16;
    const int tid = threadIdx.x;

    for (int idx = tid; idx < 2048; idx += 384) {
        int t = idx >> 7, c = idx & 127;
        xn[t * 132 + c] = x[(base + t) * CDIM + c];
    }
    __syncthreads();
    if (tid < 16) {
        float s = 0.f;
        for (int c = 0; c < 128; c++) s += xn[tid * 132 + c];
        float m = s * (1.f / 128.f);
        float v = 0.f;
        for (int c = 0; c < 128; c++) { float d = xn[tid * 132 + c] - m; v += d * d; }
        mu[tid] = m;
        rs[tid] = rsqrtf(v * (1.f / 128.f) + LEPS);
    }
    __syncthreads();
    for (int idx = tid; idx < 2048; idx += 384) {
        int t = idx >> 7, c = idx & 127;
        xn[t * 132 + c] = (xn[t * 132 + c] - mu[t]) * rs[t] * g[c] + b[c];
    }
    __syncthreads();

    const int j = tid;  // 384 columns
    float acc[16];
#pragma unroll
    for (int t = 0; t < 16; t++) acc[t] = 0.f;
    for (int c = 0; c < 128; c += 4) {
        float w0 = w[(c + 0) * 384 + j];
        float w1 = w[(c + 1) * 384 + j];
        float w2 = w[(c + 2) * 384 + j];
        float w3 = w[(c + 3) * 384 + j];
#pragma unroll
        for (int t = 0; t < 16; t++) {
            float4 xv = *(const float4*)&xn[t * 132 + c];
            acc[t] += xv.x * w0 + xv.y * w1 + xv.z * w2 + xv.w * w3;
        }
    }
    float bj = wb[j];
    float sc = (j < 128) ? QSCALE : 1.f;
#pragma unroll
    for (int t = 0; t < 16; t++)
        qkv[(base + t) * 384 + j] = (acc[t] + bj) * sc;
}

// ---------------- k2: neighborhood attention, one thread per (token, head) ----------------
__global__ __launch_bounds__(256) void k2_attn(const float* __restrict__ qkv, fp rpb,
                                               float* __restrict__ attn) {
    const int gid = blockIdx.x * 256 + threadIdx.x;  // 65536
    const int head = gid & 3;
    const int token = gid >> 2;
    const int bb = token >> 12;
    const int y = (token >> 6) & 63;
    const int xx = token & 63;
    const int sy = min(max(y - 3, 0), 57);
    const int sx = min(max(xx - 3, 0), 57);

    const float4* qp = (const float4*)(qkv + token * 384 + head * HD);
    float q[32];
#pragma unroll
    for (int i = 0; i < 8; i++) {
        float4 t = qp[i];
        q[4 * i] = t.x; q[4 * i + 1] = t.y; q[4 * i + 2] = t.z; q[4 * i + 3] = t.w;
    }
    float sc[49];
    const float* rp = rpb + head * 169 + (sy - y + 6) * 13 + (sx - xx + 6);
    const int nbase = (bb << 12) + sy * 64 + sx;
#pragma unroll
    for (int dy = 0; dy < 7; dy++) {
#pragma unroll
        for (int dx = 0; dx < 7; dx++) {
            const float4* kp = (const float4*)(qkv + (nbase + dy * 64 + dx) * 384 + 128 + head * HD);
            float s = 0.f;
#pragma unroll
            for (int i = 0; i < 8; i++) {
                float4 kv = kp[i];
                s += q[4 * i] * kv.x + q[4 * i + 1] * kv.y + q[4 * i + 2] * kv.z + q[4 * i + 3] * kv.w;
            }
            sc[dy * 7 + dx] = s + rp[dy * 13 + dx];
        }
    }
    float mx = sc[0];
#pragma unroll
    for (int l = 1; l < 49; l++) mx = fmaxf(mx, sc[l]);
    float sum = 0.f;
#pragma unroll
    for (int l = 0; l < 49; l++) { sc[l] = expf(sc[l] - mx); sum += sc[l]; }
    float inv = 1.f / sum;

    float out[32];
#pragma unroll
    for (int i = 0; i < 32; i++) out[i] = 0.f;
#pragma unroll
    for (int dy = 0; dy < 7; dy++) {
#pragma unroll
        for (int dx = 0; dx < 7; dx++) {
            float p = sc[dy * 7 + dx] * inv;
            const float4* vp = (const float4*)(qkv + (nbase + dy * 64 + dx) * 384 + 256 + head * HD);
#pragma unroll
            for (int i = 0; i < 8; i++) {
                float4 vv = vp[i];
                out[4 * i] += p * vv.x; out[4 * i + 1] += p * vv.y;
                out[4 * i + 2] += p * vv.z; out[4 * i + 3] += p * vv.w;
            }
        }
    }
    float4* op = (float4*)(attn + token * CDIM + head * HD);
#pragma unroll
    for (int i = 0; i < 8; i++)
        op[i] = make_float4(out[4 * i], out[4 * i + 1], out[4 * i + 2], out[4 * i + 3]);
}

// ---------------- k3: proj + residual + LN2 stats (8 tokens per block, 128 threads) ----------------
__global__ __launch_bounds__(128) void k3_proj(const float* __restrict__ attn, fp x, fp pw, fp pb,
                                               float* __restrict__ h, float* __restrict__ stats) {
    __shared__ float at[8 * 132];
    __shared__ float ht[8 * 132];
    const int base = blockIdx.x * 8;
    const int tid = threadIdx.x;  // 128
#pragma unroll
    for (int t = 0; t < 8; t++) at[t * 132 + tid] = attn[(base + t) * CDIM + tid];
    __syncthreads();
    float acc[8];
#pragma unroll
    for (int t = 0; t < 8; t++) acc[t] = 0.f;
    for (int c = 0; c < 128; c += 4) {
        float w0 = pw[(c + 0) * 128 + tid];
        float w1 = pw[(c + 1) * 128 + tid];
        float w2 = pw[(c + 2) * 128 + tid];
        float w3 = pw[(c + 3) * 128 + tid];
#pragma unroll
        for (int t = 0; t < 8; t++) {
            float4 av = *(const float4*)&at[t * 132 + c];
            acc[t] += av.x * w0 + av.y * w1 + av.z * w2 + av.w * w3;
        }
    }
    float bj = pb[tid];
#pragma unroll
    for (int t = 0; t < 8; t++) {
        float hv = x[(base + t) * CDIM + tid] + acc[t] + bj;
        ht[t * 132 + tid] = hv;
        h[(base + t) * CDIM + tid] = hv;
    }
    __syncthreads();
    if (tid < 8) {
        float s = 0.f;
        for (int c = 0; c < 128; c++) s += ht[tid * 132 + c];
        float m = s * (1.f / 128.f);
        float v = 0.f;
        for (int c = 0; c < 128; c++) { float d = ht[tid * 132 + c] - m; v += d * d; }
        stats[(base + tid) * 2] = m;
        stats[(base + tid) * 2 + 1] = rsqrtf(v * (1.f / 128.f) + LEPS);
    }
}

// ---------------- k4: LN2 + fc1 + GELU (8 tokens per block, 512 threads) ----------------
__global__ __launch_bounds__(512) void k4_fc1(const float* __restrict__ h, const float* __restrict__ stats,
                                              fp g, fp b, fp w1, fp b1, float* __restrict__ y1) {
    __shared__ float hn[8 * 132];
    const int base = blockIdx.x * 8;
    const int tid = threadIdx.x;  // 512
    for (int idx = tid; idx < 1024; idx += 512) {
        int t = idx >> 7, c = idx & 127;
        float m = stats[(base + t) * 2], r = stats[(base + t) * 2 + 1];
        hn[t * 132 + c] = (h[(base + t) * CDIM + c] - m) * r * g[c] + b[c];
    }
    __syncthreads();
    const int j = tid;  // 512 columns
    float acc[8];
#pragma unroll
    for (int t = 0; t < 8; t++) acc[t] = 0.f;
    for (int c = 0; c < 128; c += 4) {
        float w0 = w1[(c + 0) * HID + j];
        float w1v = w1[(c + 1) * HID + j];
        float w2 = w1[(c + 2) * HID + j];
        float w3 = w1[(c + 3) * HID + j];
#pragma unroll
        for (int t = 0; t < 8; t++) {
            float4 hv = *(const float4*)&hn[t * 132 + c];
            acc[t] += hv.x * w0 + hv.y * w1v + hv.z * w2 + hv.w * w3;
        }
    }
    float bj = b1[j];
#pragma unroll
    for (int t = 0; t < 8; t++) {
        float z = acc[t] + bj;
        float ge = 0.5f * z * (1.f + erff(z * 0.70710678118654752f));
        y1[(base + t) * HID + j] = ge;
    }
}

// ---------------- k5: fc2 + residual -> out (8 tokens per block, 128 threads) ----------------
__global__ __launch_bounds__(128) void k5_fc2(const float* __restrict__ y1, const float* __restrict__ h,
                                              fp w2, fp b2, float* __restrict__ out) {
    __shared__ float yt[8 * 516];
    const int base = blockIdx.x * 8;
    const int tid = threadIdx.x;  // 128
    for (int idx = tid; idx < 4096; idx += 128) {
        int t = idx >> 9, c = idx & 511;
        yt[t * 516 + c] = y1[(base + t) * HID + c];
    }
    __syncthreads();
    float acc[8];
#pragma unroll
    for (int t = 0; t < 8; t++) acc[t] = 0.f;
    for (int c = 0; c < 512; c += 4) {
        float w0 = w2[(c + 0) * 128 + tid];
        float w1 = w2[(c + 1) * 128 + tid];
        float w2v = w2[(c + 2) * 128 + tid];
        float w3 = w2[(c + 3) * 128 + tid];
#pragma unroll
        for (int t = 0; t < 8; t++) {
            float4 yv = *(const float4*)&yt[t * 516 + c];
            acc[t] += yv.x * w0 + yv.y * w1 + yv.z * w2v + yv.w * w3;
        }
    }
    float bj = b2[tid];
#pragma unroll
    for (int t = 0; t < 8; t++)
        out[(base + t) * CDIM + tid] = h[(base + t) * CDIM + tid] + acc[t] + bj;
}

extern "C" void kernel_launch(void* const* d_in, const int* in_sizes, int n_in,
                              void* d_out, int out_size, void* d_ws, size_t ws_size,
                              hipStream_t stream) {
    fp x      = (fp)d_in[0];
    fp ln1_g  = (fp)d_in[1];
    fp ln1_b  = (fp)d_in[2];
    fp qkv_w  = (fp)d_in[3];
    fp qkv_b  = (fp)d_in[4];
    fp rpb    = (fp)d_in[5];
    fp proj_w = (fp)d_in[6];
    fp proj_b = (fp)d_in[7];
    fp ln2_g  = (fp)d_in[8];
    fp ln2_b  = (fp)d_in[9];
    fp fc1_w  = (fp)d_in[10];
    fp fc1_b  = (fp)d_in[11];
    fp fc2_w  = (fp)d_in[12];
    fp fc2_b  = (fp)d_in[13];
    float* out = (float*)d_out;

    // workspace layout (floats), with y1 aliased over dead qkv+attn:
    //   h     [0,            2M)            8 MB   (live k3..k5)
    //   stats [2M,           2M+32768)      128 KB (live k3..k4)
    //   qkv   [2M+32K,       +6.29M)        24 MB  (live k1..k2)
    //   attn  [qkv_end,      +2M)           8 MB   (live k2..k3)
    //   y1    = qkv offset   (8.39M floats) 32 MB  (live k4..k5)
    float* ws    = (float*)d_ws;
    float* h     = ws;                       // 16384*128
    float* stats = h + TOKS * CDIM;          // 16384*2
    float* qkv   = stats + TOKS * 2;         // 16384*384
    float* attn  = qkv + TOKS * 384;         // 16384*128
    float* y1    = qkv;                      // 16384*512 (aliases qkv+attn)

    k1_ln_qkv<<<TOKS / 16, 384, 0, stream>>>(x, ln1_g, ln1_b, qkv_w, qkv_b, qkv);
    k2_attn<<<TOKS * NH / 256, 256, 0, stream>>>(qkv, rpb, attn);
    k3_proj<<<TOKS / 8, 128, 0, stream>>>(attn, x, proj_w, proj_b, h, stats);
    k4_fc1<<<TOKS / 8, 512, 0, stream>>>(h, stats, ln2_g, ln2_b, fc1_w, fc1_b, y1);
    k5_fc2<<<TOKS / 8, 128, 0, stream>>>(y1, h, fc2_w, fc2_b, out);
}